// Round 5
// baseline (309.034 us; speedup 1.0000x reference)
//
#include <hip/hip_runtime.h>
#include <hip/hip_bf16.h>

typedef unsigned short ushort_t;
typedef __attribute__((ext_vector_type(8))) short short8;
typedef __attribute__((ext_vector_type(4))) float f32x4;

#define NCOMP    8
#define CIN      512
#define COUT     256
#define H        64
#define HP       66      // padded spatial dim (halo 1 each side)
#define OHW      128
#define NB       8

// Cayley-Dickson |comp| table for n=8; sign(i,j)=+1 iff i>=j.
__device__ const int d_idx8[8][8] = {
    {0,1,2,1,4,3,2,3},
    {1,0,3,2,5,4,1,2},
    {2,1,0,1,6,5,4,3},
    {3,2,1,0,7,6,5,4},
    {4,3,2,3,0,1,2,1},
    {5,4,1,2,1,0,3,2},
    {6,5,4,3,2,1,0,1},
    {7,6,5,4,3,2,1,0}};

// Tap tables: output parity p, tap index a: kernel index kh, input offset dh.
__device__ const int kh_tab[2][2] = {{1,3},{0,2}};
__device__ const int dh_tab[2][2] = {{0,-1},{1,0}};

// ---------------- prep: x -> padded, transposed, bf16 (fused halo) ----------
__global__ void prep_x2(const float* __restrict__ x, ushort_t* __restrict__ xpadT) {
    __shared__ __align__(16) ushort_t lds[64 * 512];
    const int t = threadIdx.x;        // 0..255
    const int b = blockIdx.y;
    const int ihb = blockIdx.x;       // 0..64; 64 => both pad rows

    if (ihb == 64) {                  // ih_pad = 0 and 65: full zero rows
        short8 z = {0,0,0,0,0,0,0,0};
        ushort_t* r0 = xpadT + ((size_t)b * HP + 0)  * HP * CIN;
        ushort_t* r1 = xpadT + ((size_t)b * HP + 65) * HP * CIN;
        for (int e = t; e < (HP * CIN) / 8; e += 256) {   // 4224 ushort8
            *(short8*)(r0 + e * 8) = z;
            *(short8*)(r1 + e * 8) = z;
        }
        return;
    }
    const int ih = ihb;

    // ---- phase 1: load + convert + transposed swizzled LDS store ----
    const int iv      = t & 15;       // float4 index within row (iw = 4*iv+j)
    const int ic_base = t >> 4;       // 0..15
    const float* xr = x + ((size_t)b * CIN * H + ih) * H;
#pragma unroll 8
    for (int r = 0; r < 32; ++r) {
        const int ic = r * 16 + ic_base;
        const float4 v = *(const float4*)(xr + (size_t)ic * H * H + iv * 4);
        const int swz_ic = ic ^ (iv << 3);        // g(iw) = (iw>>2)<<3 = iv*8
        __hip_bfloat16 h0 = __float2bfloat16(v.x);
        __hip_bfloat16 h1 = __float2bfloat16(v.y);
        __hip_bfloat16 h2 = __float2bfloat16(v.z);
        __hip_bfloat16 h3 = __float2bfloat16(v.w);
        lds[(iv * 4 + 0) * 512 + swz_ic] = *(ushort_t*)&h0;
        lds[(iv * 4 + 1) * 512 + swz_ic] = *(ushort_t*)&h1;
        lds[(iv * 4 + 2) * 512 + swz_ic] = *(ushort_t*)&h2;
        lds[(iv * 4 + 3) * 512 + swz_ic] = *(ushort_t*)&h3;
    }
    __syncthreads();

    // ---- phase 2: contiguous 64KB interior write + 2 halo cells ----
    ushort_t* rowc = xpadT + (((size_t)b * HP + ih + 1) * HP) * CIN; // iw_pad=0
    ushort_t* dst  = rowc + CIN;                                     // iw_pad=1
#pragma unroll
    for (int r = 0; r < 16; ++r) {
        const int e   = r * 256 + t;
        const int iw  = e >> 6;                   // constant per wave
        const int ic0 = (e & 63) * 8;
        const int off = iw * 512 + (ic0 ^ ((iw >> 2) << 3));
        *(short8*)(dst + (size_t)e * 8) = *(const short8*)(lds + off);
    }
    if (t < 128) {                                // halo cells iw_pad 0 and 65
        short8 z = {0,0,0,0,0,0,0,0};
        const int l = t & 63;
        ushort_t* hc = (t < 64) ? rowc : (rowc + 65 * CIN);
        *(short8*)(hc + l * 8) = z;
    }
}

// ---------------- prep: fused bf16 weights + bias ----------------
__global__ void prep_w(const float* __restrict__ W, const float* __restrict__ bias,
                       ushort_t* __restrict__ Abf, float* __restrict__ bbig) {
    const int t = blockIdx.x * blockDim.x + threadIdx.x;
    if (t < 4 * 64 * 256 * 32) {
        int kin = t & 31;
        int oc  = (t >> 5) & 255;
        int ks  = (t >> 13) & 63;
        int cls = t >> 19;
        int k  = ks * 32 + kin;
        int a  = k >> 10, c = (k >> 9) & 1, ic = k & 511;
        int ph = cls >> 1, pw = cls & 1;
        int kh = kh_tab[ph][a], kw = kh_tab[pw][c];
        int i = oc >> 5, co = oc & 31;
        int j = ic >> 6, ci = ic & 63;
        float s = (i >= j) ? 1.0f : -1.0f;
        float v = s * W[(((size_t)(d_idx8[i][j] * 64 + ci) * 32 + co) * 4 + kh) * 4 + kw];
        __hip_bfloat16 h = __float2bfloat16(v);
        Abf[t] = *(ushort_t*)&h;
    }
    if (t < COUT) {
        int i = t >> 5, co = t & 31;
        float acc = 0.0f;
        for (int j = 0; j < NCOMP; ++j)
            acc += ((i >= j) ? 1.0f : -1.0f) * bias[d_idx8[i][j] * 32 + co];
        bbig[t] = acc;
    }
}

// ---------------- main: 256x256-tile implicit-GEMM, 4-buffer counted-vmcnt,
// ---------------- 2 barrier-delimited phases per K-step (m201 pattern) -----
__device__ __forceinline__ void async16(void* lds_dst, const void* g_src) {
    __builtin_amdgcn_global_load_lds(
        (const __attribute__((address_space(1))) unsigned int*)g_src,
        (__attribute__((address_space(3))) unsigned int*)lds_dst,
        16, 0, 0);
}

// Stage step NS's tiles into 32KB buffer at byte base CB (4 x async16/thread).
#define STAGE(NS, CB)                                                          \
  {                                                                            \
    const int ns_  = (NS);                                                     \
    const int na_  = ns_ >> 5;                                                 \
    const int ncb_ = (ns_ >> 4) & 1;                                           \
    const int go_  = ((na_ ? dh1 : dh0) * HP + (ncb_ ? dw1 : dw0)) * CIN       \
                     + (ns_ & 15) * 32;                                        \
    const ushort_t* nap_ = Abf_t + (size_t)ns_ * 8192;                         \
    async16(sb + (CB) + t * 16,         nap_);                                 \
    async16(sb + (CB) + 8192 + t * 16,  nap_ + 4096);                          \
    async16(sb + (CB) + 16384 + t * 16, base_lo + go_);                        \
    async16(sb + (CB) + 24576 + t * 16, base_hi + go_);                        \
  }

// 16-MFMA quadrant cluster: rows [SM0, SM0+4) x all 4 sn.
#define MFMA16(SM0)                                                            \
    _Pragma("unroll")                                                          \
    for (int sm = 0; sm < 4; ++sm)                                             \
      _Pragma("unroll")                                                        \
      for (int sn = 0; sn < 4; ++sn)                                           \
        acc[(SM0) + sm][sn] = __builtin_amdgcn_mfma_f32_16x16x32_bf16(         \
            af_[sm], bf_[sn], acc[(SM0) + sm][sn], 0, 0, 0);

// One K-step, split into 2 barrier-delimited phases (template pattern):
//   phase: {ds_reads -> s_barrier -> lgkmcnt(0) -> sched_barrier(0) ->
//           setprio(1) -> 16 MFMA -> setprio(0) -> barrier}
// Rule #18: sched_barrier(0) immediately after the inline-asm lgkmcnt(0)
// (compiler otherwise hoists register-only MFMA past it).
// Trailing barrier of phase 2 is provided by the next step's WAITBAR.
#define STEP_BODY(CB)                                                          \
  {                                                                            \
    short8 bf_[4];                                                             \
    {                                                                          \
      short8 af_[4];                                                           \
      _Pragma("unroll")                                                        \
      for (int s = 0; s < 4; ++s) {                                            \
        af_[s] = *(const short8*)(sb + (CB) + aoff + s * 1024);                \
        bf_[s] = *(const short8*)(sb + (CB) + boff + s * 1024);                \
      }                                                                        \
      __builtin_amdgcn_s_barrier();                                            \
      asm volatile("s_waitcnt lgkmcnt(0)" ::: "memory");                       \
      __builtin_amdgcn_sched_barrier(0);                                       \
      __builtin_amdgcn_s_setprio(1);                                           \
      MFMA16(0)                                                                \
      __builtin_amdgcn_s_setprio(0);                                           \
      __builtin_amdgcn_sched_barrier(0);                                       \
      __builtin_amdgcn_s_barrier();                                            \
    }                                                                          \
    {                                                                          \
      short8 af_[4];                                                           \
      _Pragma("unroll")                                                        \
      for (int s = 0; s < 4; ++s)                                              \
        af_[s] = *(const short8*)(sb + (CB) + aoff + (4 + s) * 1024);          \
      __builtin_amdgcn_s_barrier();                                            \
      asm volatile("s_waitcnt lgkmcnt(0)" ::: "memory");                       \
      __builtin_amdgcn_sched_barrier(0);                                       \
      __builtin_amdgcn_s_setprio(1);                                           \
      MFMA16(4)                                                                \
      __builtin_amdgcn_s_setprio(0);                                           \
      __builtin_amdgcn_sched_barrier(0);                                       \
    }                                                                          \
  }

// Step-boundary counted wait + barrier (T4: never drain to 0 mid-loop).
// vmcnt(8): step n's 4 loads retired; steps n+1/n+2's 8 stay in flight.
#define WAITBAR(N)                                                             \
  asm volatile("s_waitcnt vmcnt(" #N ")" ::: "memory");                        \
  __builtin_amdgcn_s_barrier();                                                \
  __builtin_amdgcn_sched_barrier(0);

__launch_bounds__(512, 2)
__global__ void htconv_mfma(const ushort_t* __restrict__ xpadT,
                            const ushort_t* __restrict__ Abf,
                            const float* __restrict__ bbig,
                            float* __restrict__ out) {
    // Four 32KB buffers (A 16KB | B 16KB each) = 128KB LDS.
    __shared__ __align__(16) ushort_t smem[65536];
    char* sb = (char*)smem;

    const int t     = threadIdx.x;            // 0..511
    const int ntile = blockIdx.x;             // 0..15 -> ohh0 = 4*ntile
    const int cls   = blockIdx.z & 3;
    const int b     = blockIdx.z >> 2;
    const int ph = cls >> 1, pw = cls & 1;
    const int ohh0 = ntile * 4;

    // ---- staging addresses ----
    const int srcc = (((t & 3) ^ ((t >> 3) & 3)) * 8);  // pre-swizzled k-chunk (elems)
    const ushort_t* Abf_t =
        Abf + ((size_t)cls * 64) * 8192 + ((size_t)(t >> 2)) * 32 + srcc;

    const int dh0 = dh_tab[ph][0], dh1 = dh_tab[ph][1];
    const int dw0 = dh_tab[pw][0], dw1 = dh_tab[pw][1];
    const int oww = (t >> 2) & 63;            // pixel col 0..63
    const int rlo = t >> 8;                   // sub-row 0/1 (first B load); +2 for second
    const ushort_t* base_lo =
        xpadT + (((size_t)b * HP + ohh0 + rlo + 1) * HP + oww + 1) * CIN + srcc;
    const ushort_t* base_hi = base_lo + (size_t)2 * HP * CIN;

    // ---- fragment read offsets (bytes within a buffer) ----
    const int lane = t & 63, wave = t >> 6;   // 8 waves: 2 M-warps x 4 N-warps
    const int wm = wave >> 2, wn = wave & 3;
    const int col = lane & 15, quad = lane >> 4;
    const int soff = (quad ^ ((col >> 1) & 3)) * 16;    // swizzled 16B chunk
    const int aoff = (wm * 128 + col) * 64 + soff;            // A rows [wm*128, +128)
    const int boff = 16384 + (wn * 64 + col) * 64 + soff;     // B pixels [wn*64, +64)

    f32x4 acc[8][4];
#pragma unroll
    for (int i = 0; i < 8; ++i)
#pragma unroll
        for (int j = 0; j < 4; ++j)
            acc[i][j] = (f32x4){0.f, 0.f, 0.f, 0.f};

    // ---- prologue: stage steps 0,1,2 into buffers 0,1,2 (12 loads in flight) ----
    STAGE(0, 0);
    STAGE(1, 32768);
    STAGE(2, 65536);

    // ---- 64 K-steps: step s consumes buf s%4, stages s+3 into (s+3)%4. ----
#pragma unroll 1
    for (int i = 0; i < 15; ++i) {
        const int n = 4 * i;
        WAITBAR(8); STAGE(n + 3, 98304); STEP_BODY(0);
        WAITBAR(8); STAGE(n + 4, 0);     STEP_BODY(32768);
        WAITBAR(8); STAGE(n + 5, 32768); STEP_BODY(65536);
        WAITBAR(8); STAGE(n + 6, 65536); STEP_BODY(98304);
    }
    // steps 60..63
    WAITBAR(8); STAGE(63, 98304); STEP_BODY(0);       // step 60
    WAITBAR(8);                   STEP_BODY(32768);   // step 61
    WAITBAR(4);                   STEP_BODY(65536);   // step 62
    WAITBAR(0);                   STEP_BODY(98304);   // step 63

    // ---- epilogue: bias + stride-2 scatter store ----
    const int oh = 2 * (ohh0 + wn) + ph;
#pragma unroll
    for (int sm = 0; sm < 8; ++sm) {
#pragma unroll
        for (int r = 0; r < 4; ++r) {
            const int occ = wm * 128 + sm * 16 + quad * 4 + r;
            const float bv = bbig[occ];
            float* obase = out + (((size_t)b * COUT + occ) * OHW + oh) * OHW + pw;
#pragma unroll
            for (int sn = 0; sn < 4; ++sn) {
                const int owi = sn * 16 + col;          // pixel col 0..63
                obase[2 * owi] = acc[sm][sn][r] + bv;
            }
        }
    }
}

extern "C" void kernel_launch(void* const* d_in, const int* in_sizes, int n_in,
                              void* d_out, int out_size, void* d_ws, size_t ws_size,
                              hipStream_t stream) {
    const float* x    = (const float*)d_in[0];  // [8,512,64,64]
    const float* W    = (const float*)d_in[1];  // [8,64,32,4,4]
    const float* bias = (const float*)d_in[2];  // [8,32]
    float* out = (float*)d_out;                 // [8,256,128,128]

    ushort_t* xpadT = (ushort_t*)d_ws;                       // 8*66*66*512 elems
    ushort_t* Abf   = xpadT + (size_t)NB * HP * HP * CIN;    // 4*64*256*32 elems
    float*    bbig  = (float*)(Abf + (size_t)4 * 64 * 256 * 32);

    prep_x2<<<dim3(65, NB), 256, 0, stream>>>(x, xpadT);
    prep_w<<<dim3((4 * 64 * 256 * 32) / 256), 256, 0, stream>>>(W, bias, Abf, bbig);
    htconv_mfma<<<dim3(16, 1, 32), 512, 0, stream>>>(xpadT, Abf, bbig, out);
}